// Round 1
// baseline (313.164 us; speedup 1.0000x reference)
//
#include <hip/hip_runtime.h>

// Dynamic conv2d: B=32, C=128, H=W=56, O=128, K(banks)=2, 3x3 pad1 stride1.
// Stages: pool -> tiny MLP/softmax -> weight aggregation (bf16) -> MFMA conv.

#define B_ 32
#define C_ 128
#define O_ 128
#define SP_ 3136   // 56*56

typedef __bf16  bf16x8 __attribute__((ext_vector_type(8)));
typedef float   f32x4  __attribute__((ext_vector_type(4)));

__device__ __forceinline__ short f2bf(float f) {
  unsigned u = __float_as_uint(f);
  u += 0x7fffu + ((u >> 16) & 1u);
  return (short)(u >> 16);
}

// ---------------- Kernel 1: global average pool ----------------
// one block per (b,c) row: 3136 floats -> mean
__global__ __launch_bounds__(256) void pool_k(const float* __restrict__ x,
                                              float* __restrict__ pooled) {
  const int bc = blockIdx.x;                       // 0..4095
  const float4* xv = reinterpret_cast<const float4*>(x + (size_t)bc * SP_);
  float s = 0.f;
  for (int i = threadIdx.x; i < 784; i += 256) {
    float4 v = xv[i];
    s += v.x + v.y + v.z + v.w;
  }
  __shared__ float red[256];
  red[threadIdx.x] = s;
  __syncthreads();
  for (int st = 128; st > 0; st >>= 1) {
    if (threadIdx.x < st) red[threadIdx.x] += red[threadIdx.x + st];
    __syncthreads();
  }
  if (threadIdx.x == 0) pooled[bc] = red[0] * (1.f / 3136.f);
}

// ---------------- Kernel 2: attention MLP + softmax + agg bias ----------------
__global__ __launch_bounds__(128) void attn_k(const float* __restrict__ pooled,
                                              const float* __restrict__ fc1,
                                              const float* __restrict__ fc2,
                                              const float* __restrict__ cbias,
                                              const float* __restrict__ dbias,
                                              float* __restrict__ attn,
                                              float* __restrict__ aggb) {
  __shared__ float hid_s[1024];   // [b][32]
  __shared__ float lg[64];        // [b][2]
  __shared__ float at[64];        // [b][2]
  const int tid = threadIdx.x;

  for (int r = tid; r < 1024; r += 128) {
    int b = r >> 5, hd = r & 31;
    float s = 0.f;
    for (int c = 0; c < C_; ++c) s += pooled[b * C_ + c] * fc1[hd * C_ + c];
    hid_s[r] = fmaxf(s, 0.f);
  }
  __syncthreads();
  if (tid < 64) {
    int b = tid >> 1, k = tid & 1;
    float s = 0.f;
    for (int h = 0; h < 32; ++h) s += hid_s[b * 32 + h] * fc2[k * 32 + h];
    lg[tid] = s;
  }
  __syncthreads();
  if (tid < 32) {
    float l0 = lg[tid * 2] * (1.f / 31.f);
    float l1 = lg[tid * 2 + 1] * (1.f / 31.f);
    float m = fmaxf(l0, l1);
    float e0 = __expf(l0 - m), e1 = __expf(l1 - m);
    float inv = 1.f / (e0 + e1);
    at[tid * 2] = e0 * inv;  at[tid * 2 + 1] = e1 * inv;
    attn[tid * 2] = e0 * inv; attn[tid * 2 + 1] = e1 * inv;
  }
  __syncthreads();
  for (int i = tid; i < B_ * O_; i += 128) {
    int b = i >> 7, o = i & 127;
    aggb[i] = at[b * 2] * cbias[o] + at[b * 2 + 1] * dbias[o];
  }
}

// ---------------- Kernel 3: weight aggregation -> bf16 [b][ij][o][c] ----------------
__global__ __launch_bounds__(256) void wagg_k(const float* __restrict__ w0,
                                              const float* __restrict__ w1,
                                              const float* __restrict__ attn,
                                              short* __restrict__ Wb) {
  const int idx = blockIdx.x * 256 + threadIdx.x;  // < 32*9*128*128
  const int c  = idx & 127;
  const int o  = (idx >> 7) & 127;
  const int t  = idx >> 14;        // b*9 + ij
  const int ij = t % 9;
  const int b  = t / 9;
  const float a0 = attn[b * 2], a1 = attn[b * 2 + 1];
  const int widx = (o * C_ + c) * 9 + ij;          // [1,O,C,3,3] flat
  Wb[idx] = f2bf(a0 * w0[widx] + a1 * w1[widx]);
}

// ---------------- Kernel 4: per-sample conv via MFMA shift-GEMM ----------------
// grid (14 h-tiles, 32 samples), 256 threads = 4 waves (2M x 2N).
// Block output: [128 o] x [4 rows x 56 cols = 224 positions].
// LDS x-tile: rows h0-1..h0+4 (6), cols -1..56 (58), c-chunk 32, pad c to 40.
__global__ __launch_bounds__(256) void conv_k(const float* __restrict__ x,
                                              const short* __restrict__ Wb,
                                              const float* __restrict__ aggb,
                                              float* __restrict__ out) {
  const int ht  = blockIdx.x;           // 0..13
  const int b   = blockIdx.y;           // 0..31
  const int h0  = ht * 4;
  const int tid  = threadIdx.x;
  const int lane = tid & 63;
  const int wv   = tid >> 6;
  const int obase = (wv >> 1) * 64;     // wave M offset
  const int nbase = (wv & 1) * 112;     // wave N offset
  const int l15 = lane & 15;
  const int lk  = (lane >> 4) * 8;      // k sub-offset within 32-chunk

  __shared__ short xs[6 * 58 * 40];     // 27840 B

  // per-n LDS element offsets (center tap), lane-resolved
  int boff[7];
#pragma unroll
  for (int n = 0; n < 7; ++n) {
    int p  = nbase + n * 16 + l15;      // 0..223
    int hl = p / 56, wl = p - hl * 56;
    boff[n] = ((hl + 1) * 58 + (wl + 1)) * 40 + lk;
  }

  f32x4 acc[4][7];
#pragma unroll
  for (int m = 0; m < 4; ++m)
#pragma unroll
    for (int n = 0; n < 7; ++n)
      acc[m][n] = f32x4{0.f, 0.f, 0.f, 0.f};

  for (int cc = 0; cc < 4; ++cc) {
    const int c0 = cc * 32;
    if (cc) __syncthreads();
    // stage fp32 -> bf16 LDS, zero-filled halo
    for (int i = tid; i < 6 * 58 * 32; i += 256) {
      int c   = i / 348;                // 348 = 6*58
      int rem = i - c * 348;
      int r   = rem / 58;
      int wc  = rem - r * 58;
      int h = h0 - 1 + r;
      int w = wc - 1;
      float v = 0.f;
      if ((unsigned)h < 56u && (unsigned)w < 56u)
        v = x[((b * C_ + c0 + c) * 56 + h) * 56 + w];
      xs[(r * 58 + wc) * 40 + c] = f2bf(v);
    }
    __syncthreads();

    const short* wb0 = Wb + (b * 9) * (O_ * C_) + c0 + lk;
#pragma unroll
    for (int ij = 0; ij < 9; ++ij) {
      const int di = ij / 3 - 1, dj = ij % 3 - 1;
      const int shift = (di * 58 + dj) * 40;
      bf16x8 af[4];
#pragma unroll
      for (int m = 0; m < 4; ++m)
        af[m] = *reinterpret_cast<const bf16x8*>(
            wb0 + ij * (O_ * C_) + (obase + m * 16 + l15) * C_);
#pragma unroll
      for (int n = 0; n < 7; ++n) {
        bf16x8 bfr = *reinterpret_cast<const bf16x8*>(&xs[boff[n] + shift]);
#pragma unroll
        for (int m = 0; m < 4; ++m)
          acc[m][n] = __builtin_amdgcn_mfma_f32_16x16x32_bf16(af[m], bfr, acc[m][n], 0, 0, 0);
      }
    }
  }

  // epilogue: add aggregated bias, store fp32
  const int r4 = (lane >> 4) * 4;
#pragma unroll
  for (int m = 0; m < 4; ++m) {
    float bias[4];
#pragma unroll
    for (int j = 0; j < 4; ++j)
      bias[j] = aggb[b * O_ + obase + m * 16 + r4 + j];
#pragma unroll
    for (int n = 0; n < 7; ++n) {
      int p = nbase + n * 16 + l15;
      int h = h0 + p / 56, w = p % 56;
#pragma unroll
      for (int j = 0; j < 4; ++j) {
        int o = obase + m * 16 + r4 + j;
        out[((size_t)(b * O_ + o) * 56 + h) * 56 + w] = acc[m][n][j] + bias[j];
      }
    }
  }
}

extern "C" void kernel_launch(void* const* d_in, const int* in_sizes, int n_in,
                              void* d_out, int out_size, void* d_ws, size_t ws_size,
                              hipStream_t stream) {
  const float* x    = (const float*)d_in[0];
  const float* cw   = (const float*)d_in[1];
  const float* cb   = (const float*)d_in[2];
  const float* dw   = (const float*)d_in[3];
  const float* db   = (const float*)d_in[4];
  const float* fc1  = (const float*)d_in[5];
  const float* fc2  = (const float*)d_in[6];
  float* out = (float*)d_out;

  // workspace layout (floats): pooled[4096] | attn[64] | aggb[4096] | Wb (bf16, 16B-aligned)
  float* ws     = (float*)d_ws;
  float* pooled = ws;
  float* attn   = ws + 4096;
  float* aggb   = ws + 4096 + 64;
  short* Wb     = (short*)(ws + 8256);   // byte offset 33024 (16B aligned); needs ~9.44 MB

  pool_k<<<B_ * C_, 256, 0, stream>>>(x, pooled);
  attn_k<<<1, 128, 0, stream>>>(pooled, fc1, fc2, cb, db, attn, aggb);
  wagg_k<<<(B_ * 9 * O_ * C_) / 256, 256, 0, stream>>>(cw, dw, attn, Wb);
  conv_k<<<dim3(14, B_), 256, 0, stream>>>(x, Wb, aggb, out);
}

// Round 2
// 238.760 us; speedup vs baseline: 1.3116x; 1.3116x over previous
//
#include <hip/hip_runtime.h>

// Dynamic conv2d: B=32, C=128, H=W=56, O=128, K(banks)=2, 3x3 pad1 stride1.
// Pipeline: convert(x->bf16 NHWC + row sums) -> pool reduce -> attn MLP ->
//           weight agg (bf16) -> MFMA conv (double-buffered LDS).

#define B_ 32
#define C_ 128
#define O_ 128
#define SP_ 3136   // 56*56

typedef __bf16  bf16x8 __attribute__((ext_vector_type(8)));
typedef short   short8 __attribute__((ext_vector_type(8)));
typedef float   f32x4  __attribute__((ext_vector_type(4)));

__device__ __forceinline__ short f2bf(float f) {
  unsigned u = __float_as_uint(f);
  u += 0x7fffu + ((u >> 16) & 1u);
  return (short)(u >> 16);
}
__device__ __forceinline__ float bf2f(short s) {
  return __uint_as_float(((unsigned)(unsigned short)s) << 16);
}

// ---------------- convert: x fp32 NCHW -> xh bf16 NHWC, + per-(b,h,c) row sums
// grid (56 h, 32 b), 256 threads
__global__ __launch_bounds__(256) void convert_k(const float* __restrict__ x,
                                                 short* __restrict__ xh,
                                                 float* __restrict__ partial) {
  const int h = blockIdx.x, b = blockIdx.y;
  const int tid = threadIdx.x;
  __shared__ short lc[C_ * 58];                 // [c][w] pad 58
  const float* xp = x + (size_t)b * C_ * SP_ + h * 56;
  for (int i = tid; i < C_ * 56; i += 256) {
    int c = i / 56, w = i - c * 56;
    lc[c * 58 + w] = f2bf(xp[(size_t)c * SP_ + w]);
  }
  __syncthreads();
  if (tid < C_) {
    float s = 0.f;
    for (int w = 0; w < 56; ++w) s += bf2f(lc[tid * 58 + w]);
    partial[((size_t)b * 56 + h) * C_ + tid] = s;
  }
  short* xo = xh + ((size_t)b * 56 + h) * 56 * C_;
  for (int u = tid; u < 896; u += 256) {        // 56 w x 16 c-parts
    int w = u >> 4, cp = (u & 15) * 8;
    short8 v;
#pragma unroll
    for (int k = 0; k < 8; ++k) v[k] = lc[(cp + k) * 58 + w];
    *reinterpret_cast<short8*>(xo + w * C_ + cp) = v;
  }
}

// ---------------- pool reduce: partial[b][h][c] -> pooled[b][c]
__global__ __launch_bounds__(256) void pool_reduce_k(const float* __restrict__ partial,
                                                     float* __restrict__ pooled) {
  const int b = blockIdx.x, tid = threadIdx.x;
  const int c = tid & 127, half = tid >> 7;
  float s = 0.f;
  for (int hh = half * 28; hh < half * 28 + 28; ++hh)
    s += partial[((size_t)b * 56 + hh) * C_ + c];
  __shared__ float red[256];
  red[tid] = s;
  __syncthreads();
  if (tid < 128) pooled[b * C_ + tid] = (red[tid] + red[tid + 128]) * (1.f / 3136.f);
}

// ---------------- legacy pool (fallback path): mean over HW per (b,c)
__global__ __launch_bounds__(256) void pool_k(const float* __restrict__ x,
                                              float* __restrict__ pooled) {
  const int bc = blockIdx.x;
  const float4* xv = reinterpret_cast<const float4*>(x + (size_t)bc * SP_);
  float s = 0.f;
  for (int i = threadIdx.x; i < 784; i += 256) {
    float4 v = xv[i];
    s += v.x + v.y + v.z + v.w;
  }
  __shared__ float red[256];
  red[threadIdx.x] = s;
  __syncthreads();
  for (int st = 128; st > 0; st >>= 1) {
    if (threadIdx.x < st) red[threadIdx.x] += red[threadIdx.x + st];
    __syncthreads();
  }
  if (threadIdx.x == 0) pooled[bc] = red[0] * (1.f / 3136.f);
}

// ---------------- attn MLP + softmax + aggregated bias ----------------
__global__ __launch_bounds__(256) void attn_k(const float* __restrict__ pooled,
                                              const float* __restrict__ fc1,
                                              const float* __restrict__ fc2,
                                              const float* __restrict__ cbias,
                                              const float* __restrict__ dbias,
                                              float* __restrict__ attn,
                                              float* __restrict__ aggb) {
  __shared__ float fc1s[32 * C_];
  __shared__ float ps[B_ * C_];
  __shared__ float hid[B_ * 32];
  __shared__ float lg[64];
  __shared__ float at[64];
  const int tid = threadIdx.x;
  for (int i = tid; i < 32 * C_; i += 256) fc1s[i] = fc1[i];
  for (int i = tid; i < B_ * C_; i += 256) ps[i] = pooled[i];
  __syncthreads();
#pragma unroll
  for (int q = 0; q < 4; ++q) {
    int id = q * 256 + tid;                 // b*32 + hd
    int b = id >> 5, hd = id & 31;
    const float4* pa = reinterpret_cast<const float4*>(&ps[b * C_]);
    const float4* fa = reinterpret_cast<const float4*>(&fc1s[hd * C_]);
    float s = 0.f;
#pragma unroll
    for (int i = 0; i < 32; ++i) {
      float4 a = pa[i], f = fa[i];
      s += a.x * f.x + a.y * f.y + a.z * f.z + a.w * f.w;
    }
    hid[id] = fmaxf(s, 0.f);
  }
  __syncthreads();
  if (tid < 64) {
    int b = tid >> 1, k = tid & 1;
    float s = 0.f;
    for (int hh = 0; hh < 32; ++hh) s += hid[b * 32 + hh] * fc2[k * 32 + hh];
    lg[tid] = s;
  }
  __syncthreads();
  if (tid < 32) {
    float l0 = lg[tid * 2] * (1.f / 31.f);
    float l1 = lg[tid * 2 + 1] * (1.f / 31.f);
    float m = fmaxf(l0, l1);
    float e0 = __expf(l0 - m), e1 = __expf(l1 - m);
    float inv = 1.f / (e0 + e1);
    at[tid * 2] = e0 * inv;     at[tid * 2 + 1] = e1 * inv;
    attn[tid * 2] = e0 * inv;   attn[tid * 2 + 1] = e1 * inv;
  }
  __syncthreads();
  for (int i = tid; i < B_ * O_; i += 256) {
    int b = i >> 7, o = i & 127;
    aggb[i] = at[b * 2] * cbias[o] + at[b * 2 + 1] * dbias[o];
  }
}

// ---------------- weight aggregation -> bf16 Wb[b][ij][o][c] ----------------
// grid 256 = 32 b x 8 o-groups, 256 threads
__global__ __launch_bounds__(256) void wagg_k(const float* __restrict__ w0,
                                              const float* __restrict__ w1,
                                              const float* __restrict__ attn,
                                              short* __restrict__ Wb) {
  const int b = blockIdx.x >> 3, og = blockIdx.x & 7;
  const int o0 = og * 16;
  const int tid = threadIdx.x;
  const float a0 = attn[b * 2], a1 = attn[b * 2 + 1];
  __shared__ short wl[9 * 16 * C_];             // [ij][o-o0][c]
#pragma unroll
  for (int it = 0; it < 8; ++it) {
    int r = it * 256 + tid;                     // (o-o0)*128 + c
    int o = o0 + (r >> 7), c = r & 127;
    size_t base = ((size_t)o * C_ + c) * 9;
#pragma unroll
    for (int j = 0; j < 9; ++j) {
      float v = a0 * w0[base + j] + a1 * w1[base + j];
      wl[j * 2048 + r] = f2bf(v);
    }
  }
  __syncthreads();
#pragma unroll
  for (int it = 0; it < 9; ++it) {
    int u = it * 256 + tid;                     // ij*256 + v
    int ij = u >> 8, v = (u & 255) * 8;
    *reinterpret_cast<short8*>(Wb + (((size_t)b * 9 + ij) * O_ + o0) * C_ + v) =
        *reinterpret_cast<const short8*>(&wl[ij * 2048 + v]);
  }
}

// ---------------- conv (fast): NHWC bf16 source, double-buffered LDS ----------------
// grid (14 h-tiles, 32 b), 256 threads = 4 waves (2M x 2N).
// Block output: 128 o x (4 rows x 56 cols = 224 pos). LDS tile: 348 pos x 32 c,
// rows padded to 40 el (80 B) for bank spread; 2 buffers.
#define POSN 348          // 6*58
#define ROWP 40           // padded c-elements per pos
#define BUFE (POSN*ROWP)  // 13920 elements per buffer
__global__ __launch_bounds__(256) void conv_fast_k(const short* __restrict__ xh,
                                                   const short* __restrict__ Wb,
                                                   const float* __restrict__ aggb,
                                                   float* __restrict__ out) {
  const int ht = blockIdx.x, b = blockIdx.y;
  const int h0 = ht * 4;
  const int tid = threadIdx.x;
  const int lane = tid & 63, wv = tid >> 6;
  const int obase = (wv >> 1) * 64;
  const int nbase = (wv & 1) * 112;
  const int l15 = lane & 15, g = lane >> 4, lk = g * 8;

  __shared__ short xs[2 * BUFE];                // 55680 B

  // staging geometry (constant over chunks)
  const short* gsrc[6];
  bool gact[6], gval[6];
  int wb_el[6];
#pragma unroll
  for (int it = 0; it < 6; ++it) {
    int u = tid + it * 256;
    gact[it] = (u < 1392);
    int uu = gact[it] ? u : 0;
    int pos = uu >> 2, part = uu & 3;
    int r = pos / 58, wc = pos - r * 58;
    int h = h0 - 1 + r, w = wc - 1;
    gval[it] = gact[it] && (unsigned)h < 56u && (unsigned)w < 56u;
    int hc = (unsigned)h < 56u ? h : 0;
    int wcl = (unsigned)w < 56u ? w : 0;
    gsrc[it] = xh + (((size_t)b * 56 + hc) * 56 + wcl) * C_ + part * 8;
    wb_el[it] = pos * ROWP + part * 8;
  }

  // per-n LDS read bases (center tap, biased by -2360 so tap offsets are >=0)
  int bb_el[7];
#pragma unroll
  for (int n = 0; n < 7; ++n) {
    int p = nbase + n * 16 + l15;
    int hl = p / 56, wl = p - hl * 56;
    bb_el[n] = ((hl + 1) * 58 + (wl + 1)) * ROWP + lk - 2360;
  }

  f32x4 acc[4][7];
#pragma unroll
  for (int m = 0; m < 4; ++m)
#pragma unroll
    for (int n = 0; n < 7; ++n) acc[m][n] = f32x4{0.f, 0.f, 0.f, 0.f};

  short8 sreg[6];
  // prolog: load + write chunk 0 into buffer 0
#pragma unroll
  for (int it = 0; it < 6; ++it)
    if (gact[it]) sreg[it] = gval[it] ? *reinterpret_cast<const short8*>(gsrc[it]) : (short8)0;
#pragma unroll
  for (int it = 0; it < 6; ++it)
    if (gact[it]) *reinterpret_cast<short8*>(&xs[wb_el[it]]) = sreg[it];

#pragma unroll
  for (int cc = 0; cc < 4; ++cc) {
    __syncthreads();
    const int cur = cc & 1;
    if (cc < 3) {
      const int c0n = (cc + 1) * 32;
#pragma unroll
      for (int it = 0; it < 6; ++it)
        if (gact[it]) sreg[it] = gval[it] ? *reinterpret_cast<const short8*>(gsrc[it] + c0n) : (short8)0;
    }
    const short* wbb = Wb + (((size_t)b * 9) << 14) + cc * 32 + lk;
#pragma unroll
    for (int ij = 0; ij < 9; ++ij) {
      const int di = ij / 3 - 1, dj = ij % 3 - 1;
      bf16x8 af[4];
#pragma unroll
      for (int m = 0; m < 4; ++m)
        af[m] = *reinterpret_cast<const bf16x8*>(wbb + (ij << 14) + (obase + m * 16 + l15) * C_);
      const short* bp0 = &xs[cur * BUFE];
#pragma unroll
      for (int n = 0; n < 7; ++n) {
        bf16x8 bfr = *reinterpret_cast<const bf16x8*>(
            bp0 + bb_el[n] + ((di * 58 + dj) * ROWP + 2360));
#pragma unroll
        for (int m = 0; m < 4; ++m)
          acc[m][n] = __builtin_amdgcn_mfma_f32_16x16x32_bf16(af[m], bfr, acc[m][n], 0, 0, 0);
      }
    }
    if (cc < 3) {
      const int nb = (cc + 1) & 1;
#pragma unroll
      for (int it = 0; it < 6; ++it)
        if (gact[it]) *reinterpret_cast<short8*>(&xs[nb * BUFE + wb_el[it]]) = sreg[it];
    }
  }

  const int r4 = g * 4;
#pragma unroll
  for (int m = 0; m < 4; ++m) {
    float bias[4];
#pragma unroll
    for (int j = 0; j < 4; ++j) bias[j] = aggb[b * O_ + obase + m * 16 + r4 + j];
#pragma unroll
    for (int n = 0; n < 7; ++n) {
      int p = nbase + n * 16 + l15;
      int h = h0 + p / 56, w = p % 56;
#pragma unroll
      for (int j = 0; j < 4; ++j) {
        int o = obase + m * 16 + r4 + j;
        out[((size_t)(b * O_ + o) * 56 + h) * 56 + w] = acc[m][n][j] + bias[j];
      }
    }
  }
}

// ---------------- conv (fallback, fp32-source, proven) ----------------
__global__ __launch_bounds__(256) void conv_k(const float* __restrict__ x,
                                              const short* __restrict__ Wb,
                                              const float* __restrict__ aggb,
                                              float* __restrict__ out) {
  const int ht  = blockIdx.x;
  const int b   = blockIdx.y;
  const int h0  = ht * 4;
  const int tid  = threadIdx.x;
  const int lane = tid & 63;
  const int wv   = tid >> 6;
  const int obase = (wv >> 1) * 64;
  const int nbase = (wv & 1) * 112;
  const int l15 = lane & 15;
  const int lk  = (lane >> 4) * 8;

  __shared__ short xs[6 * 58 * 40];

  int boff[7];
#pragma unroll
  for (int n = 0; n < 7; ++n) {
    int p  = nbase + n * 16 + l15;
    int hl = p / 56, wl = p - hl * 56;
    boff[n] = ((hl + 1) * 58 + (wl + 1)) * 40 + lk;
  }

  f32x4 acc[4][7];
#pragma unroll
  for (int m = 0; m < 4; ++m)
#pragma unroll
    for (int n = 0; n < 7; ++n)
      acc[m][n] = f32x4{0.f, 0.f, 0.f, 0.f};

  for (int cc = 0; cc < 4; ++cc) {
    const int c0 = cc * 32;
    if (cc) __syncthreads();
    for (int i = tid; i < 6 * 58 * 32; i += 256) {
      int c   = i / 348;
      int rem = i - c * 348;
      int r   = rem / 58;
      int wc  = rem - r * 58;
      int h = h0 - 1 + r;
      int w = wc - 1;
      float v = 0.f;
      if ((unsigned)h < 56u && (unsigned)w < 56u)
        v = x[((b * C_ + c0 + c) * 56 + h) * 56 + w];
      xs[(r * 58 + wc) * 40 + c] = f2bf(v);
    }
    __syncthreads();

    const short* wb0 = Wb + (b * 9) * (O_ * C_) + c0 + lk;
#pragma unroll
    for (int ij = 0; ij < 9; ++ij) {
      const int di = ij / 3 - 1, dj = ij % 3 - 1;
      const int shift = (di * 58 + dj) * 40;
      bf16x8 af[4];
#pragma unroll
      for (int m = 0; m < 4; ++m)
        af[m] = *reinterpret_cast<const bf16x8*>(
            wb0 + ij * (O_ * C_) + (obase + m * 16 + l15) * C_);
#pragma unroll
      for (int n = 0; n < 7; ++n) {
        bf16x8 bfr = *reinterpret_cast<const bf16x8*>(&xs[boff[n] + shift]);
#pragma unroll
        for (int m = 0; m < 4; ++m)
          acc[m][n] = __builtin_amdgcn_mfma_f32_16x16x32_bf16(af[m], bfr, acc[m][n], 0, 0, 0);
      }
    }
  }

  const int r4 = (lane >> 4) * 4;
#pragma unroll
  for (int m = 0; m < 4; ++m) {
    float bias[4];
#pragma unroll
    for (int j = 0; j < 4; ++j)
      bias[j] = aggb[b * O_ + obase + m * 16 + r4 + j];
#pragma unroll
    for (int n = 0; n < 7; ++n) {
      int p = nbase + n * 16 + l15;
      int h = h0 + p / 56, w = p % 56;
#pragma unroll
      for (int j = 0; j < 4; ++j) {
        int o = obase + m * 16 + r4 + j;
        out[((size_t)(b * O_ + o) * 56 + h) * 56 + w] = acc[m][n][j] + bias[j];
      }
    }
  }
}

extern "C" void kernel_launch(void* const* d_in, const int* in_sizes, int n_in,
                              void* d_out, int out_size, void* d_ws, size_t ws_size,
                              hipStream_t stream) {
  const float* x    = (const float*)d_in[0];
  const float* cw   = (const float*)d_in[1];
  const float* cb   = (const float*)d_in[2];
  const float* dw   = (const float*)d_in[3];
  const float* db   = (const float*)d_in[4];
  const float* fc1  = (const float*)d_in[5];
  const float* fc2  = (const float*)d_in[6];
  float* out = (float*)d_out;

  float* ws     = (float*)d_ws;
  float* pooled = ws;                    // 4096 f
  float* attn   = ws + 4096;             // 64 f
  float* aggb   = ws + 4160;             // 4096 f
  float* partial = ws + 8256;            // 32*56*128 = 229376 f
  short* WbF    = (short*)(ws + 237632); // 9437184 B, byte off 950528
  short* xh     = (short*)((char*)d_ws + 950528 + 9437184);  // 25690112 B
  const size_t need_fast = 950528ull + 9437184ull + 25690112ull;

  if (ws_size >= need_fast) {
    convert_k<<<dim3(56, B_), 256, 0, stream>>>(x, xh, partial);
    pool_reduce_k<<<B_, 256, 0, stream>>>(partial, pooled);
    attn_k<<<1, 256, 0, stream>>>(pooled, fc1, fc2, cb, db, attn, aggb);
    wagg_k<<<256, 256, 0, stream>>>(cw, dw, attn, WbF);
    conv_fast_k<<<dim3(14, B_), 256, 0, stream>>>(xh, WbF, aggb, out);
  } else {
    short* WbS = (short*)(ws + 8256);    // fallback layout (9.47 MB total)
    pool_k<<<B_ * C_, 256, 0, stream>>>(x, pooled);
    attn_k<<<1, 256, 0, stream>>>(pooled, fc1, fc2, cb, db, attn, aggb);
    wagg_k<<<256, 256, 0, stream>>>(cw, dw, attn, WbS);
    conv_k<<<dim3(14, B_), 256, 0, stream>>>(x, WbS, aggb, out);
  }
}

// Round 3
// 179.422 us; speedup vs baseline: 1.7454x; 1.3307x over previous
//
#include <hip/hip_runtime.h>

// Dynamic conv2d: B=32, C=128, H=W=56, O=128, K(banks)=2, 3x3 pad1 stride1.
// convert(x->bf16 NHWC + rowsums) -> fused pool+attn -> wagg -> MFMA conv
// (global_load_lds async staging, swizzled LDS, XCD-aware block order).

#define B_ 32
#define C_ 128
#define O_ 128
#define SP_ 3136   // 56*56

typedef __bf16  bf16x8 __attribute__((ext_vector_type(8)));
typedef short   short8 __attribute__((ext_vector_type(8)));
typedef float   f32x4  __attribute__((ext_vector_type(4)));

__device__ __forceinline__ short f2bf(float f) {
  unsigned u = __float_as_uint(f);
  u += 0x7fffu + ((u >> 16) & 1u);
  return (short)(u >> 16);
}
__device__ __forceinline__ float bf2f(short s) {
  return __uint_as_float(((unsigned)(unsigned short)s) << 16);
}

#define GLOAD_LDS16(gp, lp)                                                     \
  __builtin_amdgcn_global_load_lds(                                             \
      (const __attribute__((address_space(1))) unsigned int*)(gp),              \
      (__attribute__((address_space(3))) unsigned int*)(lp), 16, 0, 0)

// ws byte offsets
#define WS_PARTIAL_F 0            // 32*56*128 floats
#define WS_ATTN_F    229376      // 64 floats
#define WS_AGGB_F    229440      // 4096 floats
#define WS_ZERO_B    934144      // 1024 B zero page
#define WS_WB_B      935168      // 9437184 B
#define WS_XH_B      10372352    // 25690112 B
#define WS_NEED      36062464ull

// ---------------- convert: x fp32 NCHW -> xh bf16 NHWC + per-(b,h,c) row sums
// grid (56 h, 32 b), 256 threads
__global__ __launch_bounds__(256) void convert_k(const float* __restrict__ x,
                                                 short* __restrict__ xh,
                                                 float* __restrict__ partial) {
  const int h = blockIdx.x, b = blockIdx.y;
  const int tid = threadIdx.x;
  __shared__ short lc[C_ * 57];                 // [c][w] pad 57 (odd granule)
  const float* xp = x + (size_t)b * C_ * SP_ + h * 56;
  // phase 1: coalesced float4 loads, scalar b16 LDS writes
#pragma unroll
  for (int q = 0; q < 7; ++q) {
    int i = q * 256 + tid;                      // c*14 + w4chunk
    int c = i / 14, w4 = (i - c * 14) * 4;
    float4 v = *reinterpret_cast<const float4*>(xp + (size_t)c * SP_ + w4);
    lc[c * 57 + w4 + 0] = f2bf(v.x);
    lc[c * 57 + w4 + 1] = f2bf(v.y);
    lc[c * 57 + w4 + 2] = f2bf(v.z);
    lc[c * 57 + w4 + 3] = f2bf(v.w);
  }
  __syncthreads();
  // phase 1.5: per-c row sums
  if (tid < C_) {
    float s = 0.f;
    for (int w = 0; w < 56; ++w) s += bf2f(lc[tid * 57 + w]);
    partial[((size_t)b * 56 + h) * C_ + tid] = s;
  }
  // phase 2: transpose out as short8 (c-contiguous)
  short* xo = xh + ((size_t)b * 56 + h) * 56 * C_;
  for (int u = tid; u < 896; u += 256) {        // 56 w x 16 c-parts
    int w = u >> 4, cp = (u & 15) * 8;
    short8 v;
#pragma unroll
    for (int k = 0; k < 8; ++k) v[k] = lc[(cp + k) * 57 + w];
    *reinterpret_cast<short8*>(xo + w * C_ + cp) = v;
  }
}

// ---------------- fused pool-reduce + attention MLP + aggregated bias ----------
// grid 32 (one block per sample)
__global__ __launch_bounds__(256) void pool_attn_k(const float* __restrict__ partial,
                                                   const float* __restrict__ fc1,
                                                   const float* __restrict__ fc2,
                                                   const float* __restrict__ cbias,
                                                   const float* __restrict__ dbias,
                                                   float* __restrict__ attn,
                                                   float* __restrict__ aggb) {
  const int b = blockIdx.x, tid = threadIdx.x;
  __shared__ float red[256];
  __shared__ float pooled_s[C_];
  __shared__ float hid[32];
  __shared__ float at[2];
  {
    const int c = tid & 127, half = tid >> 7;
    float s = 0.f;
    for (int hh = half * 28; hh < half * 28 + 28; ++hh)
      s += partial[((size_t)b * 56 + hh) * C_ + c];
    red[tid] = s;
  }
  __syncthreads();
  if (tid < C_) pooled_s[tid] = (red[tid] + red[tid + 128]) * (1.f / 3136.f);
  __syncthreads();
  if (tid < 32) {
    float s = 0.f;
    for (int c = 0; c < C_; ++c) s += pooled_s[c] * fc1[tid * C_ + c];
    hid[tid] = fmaxf(s, 0.f);
  }
  __syncthreads();
  if (tid == 0) {
    float l0 = 0.f, l1 = 0.f;
    for (int hh = 0; hh < 32; ++hh) {
      l0 += hid[hh] * fc2[hh];
      l1 += hid[hh] * fc2[32 + hh];
    }
    l0 *= (1.f / 31.f); l1 *= (1.f / 31.f);
    float m = fmaxf(l0, l1);
    float e0 = __expf(l0 - m), e1 = __expf(l1 - m);
    float inv = 1.f / (e0 + e1);
    at[0] = e0 * inv; at[1] = e1 * inv;
    attn[b * 2] = at[0]; attn[b * 2 + 1] = at[1];
  }
  __syncthreads();
  if (tid < C_)
    aggb[b * O_ + tid] = at[0] * cbias[tid] + at[1] * dbias[tid];
}

// ---------------- weight aggregation -> bf16 Wb[b][ij][o][c] ----------------
// grid 256 = 32 b x 8 o-groups, 256 threads  (proven in R2)
__global__ __launch_bounds__(256) void wagg_k(const float* __restrict__ w0,
                                              const float* __restrict__ w1,
                                              const float* __restrict__ attn,
                                              short* __restrict__ Wb) {
  const int b = blockIdx.x >> 3, og = blockIdx.x & 7;
  const int o0 = og * 16;
  const int tid = threadIdx.x;
  const float a0 = attn[b * 2], a1 = attn[b * 2 + 1];
  __shared__ short wl[9 * 16 * C_];             // [ij][o-o0][c]
#pragma unroll
  for (int it = 0; it < 8; ++it) {
    int r = it * 256 + tid;                     // (o-o0)*128 + c
    int o = o0 + (r >> 7), c = r & 127;
    size_t base = ((size_t)o * C_ + c) * 9;
#pragma unroll
    for (int j = 0; j < 9; ++j) {
      float v = a0 * w0[base + j] + a1 * w1[base + j];
      wl[j * 2048 + r] = f2bf(v);
    }
  }
  __syncthreads();
#pragma unroll
  for (int it = 0; it < 9; ++it) {
    int u = it * 256 + tid;                     // ij*256 + v
    int ij = u >> 8, v = (u & 255) * 8;
    *reinterpret_cast<short8*>(Wb + (((size_t)b * 9 + ij) * O_ + o0) * C_ + v) =
        *reinterpret_cast<const short8*>(&wl[ij * 2048 + v]);
  }
}

// ---------------- conv: async global_load_lds staging, swizzled LDS ----------
// flat grid 448 (XCD-swizzled -> b = swz/14, ht = swz%14), 256 thr = 4 waves 2Mx2N.
// Block out: 128 o x (4 rows x 56 = 224 pos). LDS tile: 348 pos x 32 c per chunk,
// granule G(p,q) = 4p + ((q + (p>>2))&3)  (16B granules, conflict-free reads).
#define TPOS 348
#define UNITS 1392            // TPOS*4 16B-units per buffer
#define BUFB 22272            // bytes per buffer (UNITS*16)
__global__ __launch_bounds__(256) void conv2_k(const char* __restrict__ wsbase,
                                               const short* __restrict__ Wb,
                                               const float* __restrict__ aggb,
                                               float* __restrict__ out) {
  const int flat = blockIdx.x;                  // 448
  const int swz = (flat & 7) * 56 + (flat >> 3);  // bijective XCD chunking
  const int b = swz / 14, ht = swz - b * 14;
  const int h0 = ht * 4;
  const int tid = threadIdx.x;
  const int lane = tid & 63, wv = tid >> 6;
  const int obase = (wv >> 1) * 64;
  const int nbase = (wv & 1) * 112;
  const int l15 = lane & 15, g = lane >> 4;

  __shared__ short xs[2 * BUFB / 2];            // 44544 B

  // staging source offsets (bytes into ws), per it; zero page for halo
  int goff[6];
  bool gact[6];
#pragma unroll
  for (int it = 0; it < 6; ++it) {
    int u = tid + it * 256;
    gact[it] = (u < UNITS);
    int uu = gact[it] ? u : 0;
    int pos = uu >> 2;
    int spart = ((uu & 3) - (uu >> 4)) & 3;     // inverse swizzle on source
    int r = pos / 58, wc = pos - r * 58;
    int h = h0 - 1 + r, w = wc - 1;
    bool val = (unsigned)h < 56u && (unsigned)w < 56u;
    goff[it] = val ? (int)(WS_XH_B + 2 * (((((b * 56 + h) * 56 + w)) << 7) + spart * 8))
                   : (int)WS_ZERO_B;
  }

  // per-n output-tile positions (lane-resolved, center tap)
  int ptile[7];
#pragma unroll
  for (int n = 0; n < 7; ++n) {
    int p = nbase + n * 16 + l15;
    int hl = p / 56, wl = p - hl * 56;
    ptile[n] = (hl + 1) * 58 + (wl + 1);
  }

  f32x4 acc[4][7];
#pragma unroll
  for (int m = 0; m < 4; ++m)
#pragma unroll
    for (int n = 0; n < 7; ++n) acc[m][n] = f32x4{0.f, 0.f, 0.f, 0.f};

  // prolog: stage chunk 0 -> buffer 0
#pragma unroll
  for (int it = 0; it < 6; ++it)
    if (gact[it])
      GLOAD_LDS16(wsbase + goff[it], (char*)xs + it * 4096 + wv * 1024);
  __syncthreads();

#pragma unroll
  for (int cc = 0; cc < 4; ++cc) {
    const int cur = cc & 1;
    if (cc < 3) {                                // async stage next chunk
      const int nb = cur ^ 1;
#pragma unroll
      for (int it = 0; it < 6; ++it)
        if (gact[it])
          GLOAD_LDS16(wsbase + goff[it] + (cc + 1) * 64,
                      (char*)xs + nb * BUFB + it * 4096 + wv * 1024);
    }
    const char* bp = (const char*)xs + cur * BUFB;
    const short* wbb = Wb + (((size_t)b * 9) << 14) + cc * 32 + g * 8;
#pragma unroll
    for (int ij = 0; ij < 9; ++ij) {
      const int sh = (ij / 3 - 1) * 58 + (ij % 3 - 1);
      bf16x8 af[4];
#pragma unroll
      for (int m = 0; m < 4; ++m)
        af[m] = *reinterpret_cast<const bf16x8*>(wbb + (ij << 14) + (obase + m * 16 + l15) * C_);
#pragma unroll
      for (int n = 0; n < 7; ++n) {
        int pp = ptile[n] + sh;
        int off = (pp << 6) + ((((pp >> 2) + g) & 3) << 4);
        bf16x8 bfr = *reinterpret_cast<const bf16x8*>(bp + off);
#pragma unroll
        for (int m = 0; m < 4; ++m)
          acc[m][n] = __builtin_amdgcn_mfma_f32_16x16x32_bf16(af[m], bfr, acc[m][n], 0, 0, 0);
      }
    }
    __syncthreads();                             // drains vmcnt (stage done) + lds reads
  }

  const int r4 = g * 4;
#pragma unroll
  for (int m = 0; m < 4; ++m) {
    float bias[4];
#pragma unroll
    for (int j = 0; j < 4; ++j) bias[j] = aggb[b * O_ + obase + m * 16 + r4 + j];
#pragma unroll
    for (int n = 0; n < 7; ++n) {
      int p = nbase + n * 16 + l15;
      int h = h0 + p / 56, w = p % 56;
#pragma unroll
      for (int j = 0; j < 4; ++j) {
        int o = obase + m * 16 + r4 + j;
        out[((size_t)(b * O_ + o) * 56 + h) * 56 + w] = acc[m][n][j] + bias[j];
      }
    }
  }
}

extern "C" void kernel_launch(void* const* d_in, const int* in_sizes, int n_in,
                              void* d_out, int out_size, void* d_ws, size_t ws_size,
                              hipStream_t stream) {
  const float* x    = (const float*)d_in[0];
  const float* cw   = (const float*)d_in[1];
  const float* cb   = (const float*)d_in[2];
  const float* dw   = (const float*)d_in[3];
  const float* db   = (const float*)d_in[4];
  const float* fc1  = (const float*)d_in[5];
  const float* fc2  = (const float*)d_in[6];
  float* out = (float*)d_out;

  char* wsb     = (char*)d_ws;
  float* partial = (float*)wsb + WS_PARTIAL_F;
  float* attn    = (float*)wsb + WS_ATTN_F;
  float* aggb    = (float*)wsb + WS_AGGB_F;
  short* Wb      = (short*)(wsb + WS_WB_B);
  short* xh      = (short*)(wsb + WS_XH_B);

  hipMemsetAsync(wsb + WS_ZERO_B, 0, 1024, stream);
  convert_k<<<dim3(56, B_), 256, 0, stream>>>(x, xh, partial);
  pool_attn_k<<<B_, 256, 0, stream>>>(partial, fc1, fc2, cb, db, attn, aggb);
  wagg_k<<<256, 256, 0, stream>>>(cw, dw, attn, Wb);
  conv2_k<<<448, 256, 0, stream>>>(wsb, Wb, aggb, out);
}

// Round 4
// 175.420 us; speedup vs baseline: 1.7852x; 1.0228x over previous
//
#include <hip/hip_runtime.h>

// Dynamic conv2d: B=32, C=128, H=W=56, O=128, K(banks)=2, 3x3 pad1 stride1.
// convert(x->bf16 NHWC + rowsums) -> fused pool+attn -> wagg -> MFMA conv
// conv: all-LDS k-step pipeline (A and B staged via global_load_lds,
// double-buffered, raw s_barrier + manual vmcnt, 2 blocks/CU).

#define B_ 32
#define C_ 128
#define O_ 128
#define SP_ 3136   // 56*56

typedef __bf16  bf16x8 __attribute__((ext_vector_type(8)));
typedef short   short8 __attribute__((ext_vector_type(8)));
typedef float   f32x4  __attribute__((ext_vector_type(4)));

__device__ __forceinline__ short f2bf(float f) {
  unsigned u = __float_as_uint(f);
  u += 0x7fffu + ((u >> 16) & 1u);
  return (short)(u >> 16);
}
__device__ __forceinline__ float bf2f(short s) {
  return __uint_as_float(((unsigned)(unsigned short)s) << 16);
}

#define GLOAD_LDS16(gp, lp)                                                     \
  __builtin_amdgcn_global_load_lds(                                             \
      (const __attribute__((address_space(1))) unsigned int*)(gp),              \
      (__attribute__((address_space(3))) unsigned int*)(lp), 16, 0, 0)

// ws byte offsets
#define WS_PARTIAL_F 0           // 32*56*128 floats
#define WS_ATTN_F    229376     // 64 floats
#define WS_AGGB_F    229440     // 4096 floats
#define WS_ZERO_B    934144     // 1024 B zero page
#define WS_WB_B      935168     // 9437184 B
#define WS_XH_B      10372352   // 25690112 B

// ---------------- convert: x fp32 NCHW -> xh bf16 NHWC + per-(b,h,c) row sums
__global__ __launch_bounds__(256) void convert_k(const float* __restrict__ x,
                                                 short* __restrict__ xh,
                                                 float* __restrict__ partial) {
  const int h = blockIdx.x, b = blockIdx.y;
  const int tid = threadIdx.x;
  __shared__ short lc[C_ * 57];
  const float* xp = x + (size_t)b * C_ * SP_ + h * 56;
#pragma unroll
  for (int q = 0; q < 7; ++q) {
    int i = q * 256 + tid;                      // c*14 + w4chunk
    int c = i / 14, w4 = (i - c * 14) * 4;
    float4 v = *reinterpret_cast<const float4*>(xp + (size_t)c * SP_ + w4);
    lc[c * 57 + w4 + 0] = f2bf(v.x);
    lc[c * 57 + w4 + 1] = f2bf(v.y);
    lc[c * 57 + w4 + 2] = f2bf(v.z);
    lc[c * 57 + w4 + 3] = f2bf(v.w);
  }
  __syncthreads();
  if (tid < C_) {
    float s = 0.f;
    for (int w = 0; w < 56; ++w) s += bf2f(lc[tid * 57 + w]);
    partial[((size_t)b * 56 + h) * C_ + tid] = s;
  }
  short* xo = xh + ((size_t)b * 56 + h) * 56 * C_;
  for (int u = tid; u < 896; u += 256) {
    int w = u >> 4, cp = (u & 15) * 8;
    short8 v;
#pragma unroll
    for (int k = 0; k < 8; ++k) v[k] = lc[(cp + k) * 57 + w];
    *reinterpret_cast<short8*>(xo + w * C_ + cp) = v;
  }
}

// ---------------- fused pool-reduce + attention MLP + aggregated bias ----------
__global__ __launch_bounds__(256) void pool_attn_k(const float* __restrict__ partial,
                                                   const float* __restrict__ fc1,
                                                   const float* __restrict__ fc2,
                                                   const float* __restrict__ cbias,
                                                   const float* __restrict__ dbias,
                                                   float* __restrict__ attn,
                                                   float* __restrict__ aggb) {
  const int b = blockIdx.x, tid = threadIdx.x;
  __shared__ float red[256];
  __shared__ float pooled_s[C_];
  __shared__ float hid[32];
  __shared__ float lg[2];
  __shared__ float at[2];
  {
    const int c = tid & 127, half = tid >> 7;
    float s = 0.f;
    for (int hh = half * 28; hh < half * 28 + 28; ++hh)
      s += partial[((size_t)b * 56 + hh) * C_ + c];
    red[tid] = s;
  }
  __syncthreads();
  if (tid < C_) pooled_s[tid] = (red[tid] + red[tid + 128]) * (1.f / 3136.f);
  __syncthreads();
  {  // fc1: 32 hd x 8 parts, each part sums 16 c (4x float4)
    const int hd = tid >> 3, part = tid & 7;
    const float4* fa = reinterpret_cast<const float4*>(fc1 + hd * C_ + part * 16);
    const float4* pa = reinterpret_cast<const float4*>(pooled_s + part * 16);
    float s = 0.f;
#pragma unroll
    for (int i = 0; i < 4; ++i) {
      float4 f = fa[i], p = pa[i];
      s += f.x * p.x + f.y * p.y + f.z * p.z + f.w * p.w;
    }
    red[tid] = s;
  }
  __syncthreads();
  if (tid < 32) {
    float v = 0.f;
#pragma unroll
    for (int j = 0; j < 8; ++j) v += red[tid * 8 + j];
    hid[tid] = fmaxf(v, 0.f);
  }
  __syncthreads();
  if (tid < 64) red[tid] = hid[tid & 31] * fc2[tid];   // fc2[k*32+h], tid = k*32+h
  __syncthreads();
  if (tid < 2) {
    float l = 0.f;
#pragma unroll
    for (int hh = 0; hh < 32; ++hh) l += red[tid * 32 + hh];
    lg[tid] = l * (1.f / 31.f);
  }
  __syncthreads();
  if (tid == 0) {
    float m = fmaxf(lg[0], lg[1]);
    float e0 = __expf(lg[0] - m), e1 = __expf(lg[1] - m);
    float inv = 1.f / (e0 + e1);
    at[0] = e0 * inv; at[1] = e1 * inv;
    attn[b * 2] = at[0]; attn[b * 2 + 1] = at[1];
  }
  __syncthreads();
  if (tid < C_)
    aggb[b * O_ + tid] = at[0] * cbias[tid] + at[1] * dbias[tid];
}

// ---------------- weight aggregation -> bf16 Wb[b][ij][o][c] ----------------
__global__ __launch_bounds__(256) void wagg_k(const float* __restrict__ w0,
                                              const float* __restrict__ w1,
                                              const float* __restrict__ attn,
                                              short* __restrict__ Wb) {
  const int b = blockIdx.x >> 3, og = blockIdx.x & 7;
  const int o0 = og * 16;
  const int tid = threadIdx.x;
  const float a0 = attn[b * 2], a1 = attn[b * 2 + 1];
  __shared__ short wl[9 * 16 * C_];
#pragma unroll
  for (int it = 0; it < 8; ++it) {
    int r = it * 256 + tid;
    int o = o0 + (r >> 7), c = r & 127;
    size_t base = ((size_t)o * C_ + c) * 9;
#pragma unroll
    for (int j = 0; j < 9; ++j) {
      float v = a0 * w0[base + j] + a1 * w1[base + j];
      wl[j * 2048 + r] = f2bf(v);
    }
  }
  __syncthreads();
#pragma unroll
  for (int it = 0; it < 9; ++it) {
    int u = it * 256 + tid;
    int ij = u >> 8, v = (u & 255) * 8;
    *reinterpret_cast<short8*>(Wb + (((size_t)b * 9 + ij) * O_ + o0) * C_ + v) =
        *reinterpret_cast<const short8*>(&wl[ij * 2048 + v]);
  }
}

// ---------------- conv: all-LDS k-step pipeline ----------------
// flat grid 448 (XCD-bijective), 256 thr = 4 waves 2Mx2N; out 128o x 224pos.
// 36 k-steps (4 c-chunks x 9 taps), K=32 each. B: 348pos x 32c swizzled
// granules, dbuf 2x22272. A: 128o x 32c swizzled granules, dbuf 2x8192.
#define TPOS 348
#define BUNITS 1392
#define BBUF 22272
#define AOFF 44544
#define ABUF 8192
__global__ __launch_bounds__(256, 2) void conv3_k(const char* __restrict__ wsbase,
                                                  const float* __restrict__ aggb,
                                                  float* __restrict__ out) {
  const int flat = blockIdx.x;
  const int swz = (flat & 7) * 56 + (flat >> 3);
  const int b = swz / 14, ht = swz - b * 14;
  const int h0 = ht * 4;
  const int tid = threadIdx.x;
  const int lane = tid & 63, wv = tid >> 6;
  const int obase = (wv >> 1) * 64;
  const int nbase = (wv & 1) * 112;
  const int l15 = lane & 15, g = lane >> 4;

  __shared__ __align__(16) char xs[AOFF + 2 * ABUF];   // 60928 B

  // ---- B staging geometry: unit u = tid + it*256 (u < 1392)
  const char* gsrcB[6];
  bool gact[6];
#pragma unroll
  for (int it = 0; it < 6; ++it) {
    int u = tid + it * 256;
    gact[it] = (u < BUNITS);
    int uu = gact[it] ? u : 0;
    int pos = uu >> 2;
    int q = ((uu & 3) - (uu >> 4)) & 3;          // inverse granule swizzle
    int r = pos / 58, wc = pos - r * 58;
    int h = h0 - 1 + r, w = wc - 1;
    bool val = (unsigned)h < 56u && (unsigned)w < 56u;
    gsrcB[it] = wsbase + (val ? (WS_XH_B + 2 * ((((b * 56 + h) * 56 + w) << 7) + q * 8))
                              : WS_ZERO_B);
  }
  // ---- A staging geometry: unit u = tid + it*256 (u < 512)
  const char* gsrcA[2];
#pragma unroll
  for (int it = 0; it < 2; ++it) {
    int u = tid + it * 256;
    int o = u >> 2;
    int q = ((u & 3) - (u >> 4)) & 3;
    gsrcA[it] = wsbase + WS_WB_B + 2 * ((size_t)b * 147456 + o * C_ + q * 8);
  }
  // ---- A read offsets (per m, step-invariant)
  int aoffR[4];
#pragma unroll
  for (int m = 0; m < 4; ++m) {
    int o = obase + m * 16 + l15;
    aoffR[m] = (o << 6) + (((g + (o >> 2)) & 3) << 4);
  }
  // ---- B read positions (center tap)
  int ptile[7];
#pragma unroll
  for (int n = 0; n < 7; ++n) {
    int p = nbase + n * 16 + l15;
    int hl = p / 56, wl = p - hl * 56;
    ptile[n] = (hl + 1) * 58 + (wl + 1);
  }

  f32x4 acc[4][7];
#pragma unroll
  for (int m = 0; m < 4; ++m)
#pragma unroll
    for (int n = 0; n < 7; ++n) acc[m][n] = f32x4{0.f, 0.f, 0.f, 0.f};

  // ---- prolog: stage B(chunk0) + A(step0), wait, barrier
#pragma unroll
  for (int it = 0; it < 6; ++it)
    if (gact[it]) GLOAD_LDS16(gsrcB[it], xs + it * 4096 + wv * 1024);
#pragma unroll
  for (int it = 0; it < 2; ++it)
    GLOAD_LDS16(gsrcA[it], xs + AOFF + it * 4096 + wv * 1024);
  asm volatile("s_waitcnt vmcnt(0)" ::: "memory");
  __builtin_amdgcn_s_barrier();

#pragma unroll
  for (int cc = 0; cc < 4; ++cc) {
#pragma unroll
    for (int ij = 0; ij < 9; ++ij) {
      const int s = cc * 9 + ij;
      const int apar = s & 1, bpar = cc & 1;
      // issue A stage for step s+1
      if (s < 35) {
        const int s2 = s + 1, cc2 = s2 / 9, ij2 = s2 - cc2 * 9;
        const int adelta = 2 * (ij2 * 16384 + cc2 * 32);
#pragma unroll
        for (int it = 0; it < 2; ++it)
          GLOAD_LDS16(gsrcA[it] + adelta,
                      xs + AOFF + ((s2 & 1) ? ABUF : 0) + it * 4096 + wv * 1024);
      }
      // issue B stage for chunk cc+1 (once per chunk)
      if (ij == 0 && cc < 3) {
#pragma unroll
        for (int it = 0; it < 6; ++it)
          if (gact[it])
            GLOAD_LDS16(gsrcB[it] + (cc + 1) * 64,
                        xs + (bpar ? 0 : BBUF) + it * 4096 + wv * 1024);
      }
      // compute step s
      const char* abuf = xs + AOFF + (apar ? ABUF : 0);
      const char* bbuf = xs + (bpar ? BBUF : 0);
      bf16x8 af[4];
#pragma unroll
      for (int m = 0; m < 4; ++m)
        af[m] = *reinterpret_cast<const bf16x8*>(abuf + aoffR[m]);
      const int sh = (ij / 3 - 1) * 58 + (ij % 3 - 1);
#pragma unroll
      for (int n = 0; n < 7; ++n) {
        int pp = ptile[n] + sh;
        int off = (pp << 6) + ((((pp >> 2) + g) & 3) << 4);
        bf16x8 bfr = *reinterpret_cast<const bf16x8*>(bbuf + off);
#pragma unroll
        for (int m = 0; m < 4; ++m)
          acc[m][n] = __builtin_amdgcn_mfma_f32_16x16x32_bf16(af[m], bfr, acc[m][n], 0, 0, 0);
      }
      // end of step: stages for s+1 must land; all waves sync
      if (s < 35) {
        asm volatile("s_waitcnt vmcnt(0)" ::: "memory");
        __builtin_amdgcn_s_barrier();
      }
    }
  }

  // ---- epilogue
  const int r4 = g * 4;
#pragma unroll
  for (int m = 0; m < 4; ++m) {
    float bias[4];
#pragma unroll
    for (int j = 0; j < 4; ++j) bias[j] = aggb[b * O_ + obase + m * 16 + r4 + j];
#pragma unroll
    for (int n = 0; n < 7; ++n) {
      int p = nbase + n * 16 + l15;
      int h = h0 + p / 56, w = p % 56;
#pragma unroll
      for (int j = 0; j < 4; ++j) {
        int o = obase + m * 16 + r4 + j;
        out[((size_t)(b * O_ + o) * 56 + h) * 56 + w] = acc[m][n][j] + bias[j];
      }
    }
  }
}

extern "C" void kernel_launch(void* const* d_in, const int* in_sizes, int n_in,
                              void* d_out, int out_size, void* d_ws, size_t ws_size,
                              hipStream_t stream) {
  const float* x    = (const float*)d_in[0];
  const float* cw   = (const float*)d_in[1];
  const float* cb   = (const float*)d_in[2];
  const float* dw   = (const float*)d_in[3];
  const float* db   = (const float*)d_in[4];
  const float* fc1  = (const float*)d_in[5];
  const float* fc2  = (const float*)d_in[6];
  float* out = (float*)d_out;

  char* wsb      = (char*)d_ws;
  float* partial = (float*)wsb + WS_PARTIAL_F;
  float* attn    = (float*)wsb + WS_ATTN_F;
  float* aggb    = (float*)wsb + WS_AGGB_F;
  short* Wb      = (short*)(wsb + WS_WB_B);
  short* xh      = (short*)(wsb + WS_XH_B);

  hipMemsetAsync(wsb + WS_ZERO_B, 0, 1024, stream);
  convert_k<<<dim3(56, B_), 256, 0, stream>>>(x, xh, partial);
  pool_attn_k<<<B_, 256, 0, stream>>>(partial, fc1, fc2, cb, db, attn, aggb);
  wagg_k<<<256, 256, 0, stream>>>(cw, dw, attn, Wb);
  conv3_k<<<448, 256, 0, stream>>>(wsb, aggb, out);
}